// Round 11
// baseline (482.802 us; speedup 1.0000x reference)
//
#include <hip/hip_runtime.h>
#include <hip/hip_bf16.h>

#define B_ 16
#define N_ 8192
#define G_ 128
#define K_ 32
#define C_ 384
#define EPSV 1e-5f

typedef __attribute__((ext_vector_type(8))) short bf16x8;
typedef __attribute__((ext_vector_type(8))) unsigned short u16x8;
typedef __attribute__((ext_vector_type(4))) float f32x4;
typedef __attribute__((ext_vector_type(2))) float f32x2;

__device__ __forceinline__ unsigned short f2b(float f){
  unsigned int u = __float_as_uint(f);
  u += 0x7fffu + ((u >> 16) & 1u);      // RNE (no NaNs in this model)
  return (unsigned short)(u >> 16);
}
__device__ __forceinline__ float b2f(unsigned short s){
  return __uint_as_float(((unsigned int)s) << 16);
}
// exact-order squared distance: ((dx*dx + dy*dy) + dz*dz), IEEE, no contraction
__device__ __forceinline__ float sq3(float dx, float dy, float dz){
  return __fadd_rn(__fadd_rn(__fmul_rn(dx,dx), __fmul_rn(dy,dy)), __fmul_rn(dz,dz));
}
__device__ __forceinline__ f32x2 pkmax(f32x2 a, f32x2 b){
  return f32x2{fmaxf(a.x,b.x), fmaxf(a.y,b.y)};
}
// total-order encode: monotone f32 -> u32 (handles negatives from cancellation)
__device__ __forceinline__ unsigned fenc(float f){
  unsigned u = __float_as_uint(f);
  return ((int)u >= 0) ? (u | 0x80000000u) : ~u;
}

// ---- full-wave DPP reductions (VALU-only; result in lane 63) ----
#define DPP_MAXU_STAGE(r, CTRL) { \
  unsigned _o = (unsigned)__builtin_amdgcn_update_dpp((int)(r), (int)(r), (CTRL), 0xf, 0xf, false); \
  (r) = ((r) > _o) ? (r) : _o; }
#define DPP_MAXU_ALL(r) \
  DPP_MAXU_STAGE(r, 0x111) DPP_MAXU_STAGE(r, 0x112) DPP_MAXU_STAGE(r, 0x114) \
  DPP_MAXU_STAGE(r, 0x118) DPP_MAXU_STAGE(r, 0x142) DPP_MAXU_STAGE(r, 0x143)
#define DPP_MINU_STAGE(r, CTRL) { \
  unsigned _o = (unsigned)__builtin_amdgcn_update_dpp((int)(r), (int)(r), (CTRL), 0xf, 0xf, false); \
  (r) = ((r) < _o) ? (r) : _o; }
#define DPP_MINU_ALL(r) \
  DPP_MINU_STAGE(r, 0x111) DPP_MINU_STAGE(r, 0x112) DPP_MINU_STAGE(r, 0x114) \
  DPP_MINU_STAGE(r, 0x118) DPP_MINU_STAGE(r, 0x142) DPP_MINU_STAGE(r, 0x143)

// ---------------- FPS (blocks 0..15) + weight-prep (blocks 16..1935) ----------------
// prep rides in fps's 191us shadow on the 240 otherwise-idle CUs.
__attribute__((amdgpu_flat_work_group_size(256,256), amdgpu_waves_per_eu(1,1)))
__global__ void fps_morton_prep_kernel(const float* __restrict__ xyz,
                                       float* __restrict__ centers_ord,
                                       const float* __restrict__ w2f,
                                       const float* __restrict__ w3f,
                                       const float* __restrict__ w4f,
                                       unsigned short* __restrict__ w2b,
                                       unsigned short* __restrict__ w3b,
                                       unsigned short* __restrict__ w4b){
  const int t = threadIdx.x;
  if (blockIdx.x >= B_){
    int i = (blockIdx.x - B_)*256 + t;
    if (i < 32768){ w2b[i] = f2b(w2f[i]); return; }
    i -= 32768;
    if (i < 262144){ w3b[i] = f2b(w3f[i]); return; }
    i -= 262144;
    if (i < 196608) w4b[i] = f2b(w4f[i]);
    return;
  }
  const int b = blockIdx.x, w = t >> 6;
  const int lane = t & 63;
  const float* xb = xyz + (size_t)b*N_*3;
  __shared__ __align__(16) float sval[2][4];
  __shared__ __align__(16) int   sidx[2][4];
  __shared__ float clx[G_], cly[G_], clz[G_];
  const int base = t*32;
  f32x2 X[16], Y[16], Z[16], D[16];
  f32x2 mmax;
  const float p0x = xb[0], p0y = xb[1], p0z = xb[2];
  {
#pragma clang fp contract(off)
    float s[96];
    const float4* src = (const float4*)(xb + (size_t)base*3);
    #pragma unroll
    for (int q = 0; q < 24; q++) ((float4*)s)[q] = src[q];
    mmax = f32x2{-1.f, -1.f};
    #pragma unroll
    for (int p = 0; p < 16; p++){
      X[p] = f32x2{s[6*p+0], s[6*p+3]};
      Y[p] = f32x2{s[6*p+1], s[6*p+4]};
      Z[p] = f32x2{s[6*p+2], s[6*p+5]};
      const f32x2 dx = X[p] - p0x, dy = Y[p] - p0y, dz = Z[p] - p0z;
      D[p] = (dx*dx + dy*dy) + dz*dz;
      mmax = pkmax(mmax, D[p]);
    }
  }
  if (t == 0){ clx[0] = p0x; cly[0] = p0y; clz[0] = p0z; }
  int buf = 0;
  for (int g = 1; g < G_; g++){
    const float v = fmaxf(mmax.x, mmax.y);
    int jl = 0;
    #pragma unroll
    for (int p = 15; p >= 0; p--){
      if (D[p].y == v) jl = 2*p+1;
      if (D[p].x == v) jl = 2*p;
    }
    const unsigned uv = __float_as_uint(v);
    unsigned r = uv;
    DPP_MAXU_ALL(r)
    const unsigned wmax = (unsigned)__builtin_amdgcn_readlane((int)r, 63);
    const unsigned long long tie = __ballot(uv == wmax);
    const int wl = __ffsll(tie) - 1;
    if (lane == wl){ sval[buf][w] = __uint_as_float(wmax); sidx[buf][w] = base + jl; }
    __syncthreads();
    const float4 vv = *(const float4*)&sval[buf][0];
    const int4   ii = *(const int4*)&sidx[buf][0];
    float bv = vv.x; int bb = ii.x;
    if (vv.y > bv){ bv = vv.y; bb = ii.y; }
    if (vv.z > bv){ bv = vv.z; bb = ii.z; }
    if (vv.w > bv){ bv = vv.w; bb = ii.w; }
    {
#pragma clang fp contract(off)
      const int ubb = __builtin_amdgcn_readfirstlane(bb);
      const float cx = xb[ubb*3], cy = xb[ubb*3+1], cz = xb[ubb*3+2];
      if (t == 0){ clx[g] = cx; cly[g] = cy; clz[g] = cz; }
      mmax = f32x2{-1.f, -1.f};
      #pragma unroll
      for (int p = 0; p < 16; p++){
        const f32x2 dx = X[p] - cx, dy = Y[p] - cy, dz = Z[p] - cz;
        const f32x2 dn = (dx*dx + dy*dy) + dz*dz;
        D[p] = f32x2{fminf(D[p].x, dn.x), fminf(D[p].y, dn.y)};
        mmax = pkmax(mmax, D[p]);
      }
    }
    buf ^= 1;
  }
  __syncthreads();
  if (t < 64){
    float mcx[2], mcy[2], mcz[2]; bool mvis[2];
    #pragma unroll
    for (int j = 0; j < 2; j++){
      const int idx = lane + j*64;
      mcx[j] = clx[idx]; mcy[j] = cly[idx]; mcz[j] = clz[idx];
      mvis[j] = (idx == 0);
    }
    float curx = clx[0], cury = cly[0], curz = clz[0];
    if (lane == 0){
      centers_ord[(size_t)b*G_*3 + 0] = curx;
      centers_ord[(size_t)b*G_*3 + 1] = cury;
      centers_ord[(size_t)b*G_*3 + 2] = curz;
    }
    for (int step = 1; step < G_; step++){
      const float d0r = sq3(__fsub_rn(mcx[0],curx), __fsub_rn(mcy[0],cury), __fsub_rn(mcz[0],curz));
      const float d1r = sq3(__fsub_rn(mcx[1],curx), __fsub_rn(mcy[1],cury), __fsub_rn(mcz[1],curz));
      const float d0 = mvis[0] ? __builtin_inff() : d0r;
      const float d1 = mvis[1] ? __builtin_inff() : d1r;
      float mv = d0; int mi = lane;
      if (d1 < mv){ mv = d1; mi = lane + 64; }
      const int wj = mi >> 6;
      const float sx = wj ? mcx[1] : mcx[0];
      const float sy = wj ? mcy[1] : mcy[0];
      const float sz = wj ? mcz[1] : mcz[0];
      const unsigned key = __float_as_uint(mv);
      unsigned r = key;
      DPP_MINU_ALL(r)
      const unsigned wmin = (unsigned)__builtin_amdgcn_readlane((int)r, 63);
      const unsigned long long tie = __ballot(key == wmin);
      int wl;
      if (__popcll(tie) == 1){
        wl = __ffsll(tie) - 1;
      } else {
        float tv = mv; int ti = mi;
        #pragma unroll
        for (int mk = 1; mk < 64; mk <<= 1){
          const float ov = __shfl_xor(tv, mk);
          const int   oi = __shfl_xor(ti, mk);
          if (ov < tv || (ov == tv && oi < ti)){ tv = ov; ti = oi; }
        }
        wl = ti & 63;
      }
      const int mbi = __builtin_amdgcn_readlane(mi, wl);
      curx = __uint_as_float((unsigned)__builtin_amdgcn_readlane((int)__float_as_uint(sx), wl));
      cury = __uint_as_float((unsigned)__builtin_amdgcn_readlane((int)__float_as_uint(sy), wl));
      curz = __uint_as_float((unsigned)__builtin_amdgcn_readlane((int)__float_as_uint(sz), wl));
      if (lane == wl){
        if ((mbi >> 6) == 0) mvis[0] = true; else mvis[1] = true;
      }
      if (lane == 0){
        centers_ord[((size_t)b*G_ + step)*3 + 0] = curx;
        centers_ord[((size_t)b*G_ + step)*3 + 1] = cury;
        centers_ord[((size_t)b*G_ + step)*3 + 2] = curz;
      }
    }
  }
}

// ---------------- KNN: contiguous ownership + DPP min tree + ballot ----------------
__global__ __launch_bounds__(256, 2) void knn_kernel(const float* __restrict__ xyz,
                                                     const float* __restrict__ centers_ord,
                                                     float* __restrict__ neigh){
  const int gp = blockIdx.x, b = blockIdx.y, t = threadIdx.x;
  const int lane = t & 63, w = t >> 6;
  __shared__ __align__(16) float sv[2][4];
  __shared__ __align__(16) int   si[2][4];
  __shared__ int list[K_];
  const float* xb = xyz + (size_t)b*N_*3;
  const float* cp = centers_ord + ((size_t)b*G_ + gp)*3;
  const float cxv = cp[0], cyv = cp[1], czv = cp[2];
  const float cc = sq3(cxv, cyv, czv);
  const int base = t*32;
  float dd[32];
  float v = __builtin_inff(); int jl = 0;
  {
    float s[96];
    const float4* src = (const float4*)(xb + (size_t)base*3);
    #pragma unroll
    for (int q = 0; q < 24; q++) ((float4*)s)[q] = src[q];
    #pragma unroll
    for (int j = 0; j < 32; j++){
      const float x = s[3*j], y = s[3*j+1], z = s[3*j+2];
      const float xx = sq3(x, y, z);
      const float dot = __fadd_rn(__fadd_rn(__fmul_rn(cxv,x), __fmul_rn(cyv,y)), __fmul_rn(czv,z));
      dd[j] = __fsub_rn(__fadd_rn(cc, xx), __fmul_rn(2.f, dot));
      if (dd[j] < v){ v = dd[j]; jl = j; }
    }
  }
  int buf = 0;
  for (int it = 0; it < K_; it++){
    const unsigned key = fenc(v);
    unsigned r = key;
    DPP_MINU_ALL(r)
    const unsigned wmin = (unsigned)__builtin_amdgcn_readlane((int)r, 63);
    const unsigned long long tie = __ballot(key == wmin);
    const int wl = __ffsll(tie) - 1;
    if (lane == wl){ sv[buf][w] = v; si[buf][w] = base + jl; }
    __syncthreads();
    const float4 vv = *(const float4*)&sv[buf][0];
    const int4   ii = *(const int4*)&si[buf][0];
    float bv = vv.x; int bb = ii.x;
    if (vv.y < bv){ bv = vv.y; bb = ii.y; }
    if (vv.z < bv){ bv = vv.z; bb = ii.z; }
    if (vv.w < bv){ bv = vv.w; bb = ii.w; }
    if (t == 0) list[it] = bb;
    if ((bb >> 5) == t){
      const int jw = bb & 31;
      #pragma unroll
      for (int j = 0; j < 32; j++) if (j == jw) dd[j] = __builtin_inff();
      v = __builtin_inff(); jl = 0;
      #pragma unroll
      for (int j = 0; j < 32; j++) if (dd[j] < v){ v = dd[j]; jl = j; }
    }
    buf ^= 1;
  }
  __syncthreads();
  if (t < K_*3){
    const int k = t / 3, d = t % 3;
    const int n = list[k];
    neigh[(((size_t)b*G_ + gp)*K_ + k)*3 + d] = __fsub_rn(xb[n*3+d], cp[d]);
  }
}

// ---------------- encoder: 3 groups/block, B-fragment double-buffered weight stream ----------------
__device__ __forceinline__ int swzA1(int row, int col){  // [32][128] bf16
  int byteo = row*256 + col*2;
  byteo ^= (row & 7) << 4;
  return byteo >> 1;
}
__device__ __forceinline__ int swzF(int row, int col){  // [32][256] bf16
  int byteo = row*512 + col*2;
  byteo ^= (row & 7) << 4;
  return byteo >> 1;
}
__device__ __forceinline__ int swzA(int row, int col){  // [32][512] bf16
  int byteo = row*1024 + col*2;
  byteo ^= (row & 7) << 4;
  return byteo >> 1;
}

#define NG3 3

__global__ __launch_bounds__(512, 2) void enc_kernel(
    const float* __restrict__ neigh, const float* __restrict__ centers_ord,
    const float* __restrict__ w1, const float* __restrict__ b1,
    const float* __restrict__ g1, const float* __restrict__ bt1,
    const float* __restrict__ m1, const float* __restrict__ v1,
    const unsigned short* __restrict__ w2b, const float* __restrict__ b2,
    const unsigned short* __restrict__ w3b, const float* __restrict__ b3,
    const float* __restrict__ g3, const float* __restrict__ bt3,
    const float* __restrict__ m3, const float* __restrict__ v3,
    const unsigned short* __restrict__ w4b, const float* __restrict__ b4,
    float* __restrict__ out)
{
  const int t = threadIdx.x;
  const int lane = t & 63, w = t >> 6, lr = lane & 15, lg = lane >> 4;
  const int gid0 = blockIdx.x*NG3;
  const int ng = min(NG3, 2048 - gid0);   // tail block: 2 groups
  // LDS overlays (lifetimes):  A1s [L1,L2) overlays A3s [L3,L4);  tok [L4,..) overlays Fl [L2,L3)
  __shared__ __align__(16) char smem[148992];
  unsigned short* A3s = (unsigned short*)smem;              // [3][32*512]
  unsigned short* A1s = (unsigned short*)smem;              // [3][32*128] (overlay)
  unsigned short* Flp = (unsigned short*)(smem + 98304);    // [3][32*256]
  unsigned short* fgb = (unsigned short*)(smem + 147456);   // [3][256]
  float* tokp = (float*)(smem + 98304);                     // [3][384] (overlay of Fl)

  // ---- L1 (3->128) + BN + ReLU -> A1s
  for (int it = t; it < NG3*256; it += 512){
    const int g = it >> 8, rem = it & 255, p = rem >> 3, c0 = (rem & 7) * 16;
    const float* pgp = neigh + (size_t)(gid0 + g)*96 + p*3;   // tail g: in-ws garbage, masked at out
    const float px = pgp[0], py = pgp[1], pz = pgp[2];
    unsigned short hv[16];
    #pragma unroll
    for (int cc = 0; cc < 16; cc++){
      const int c = c0 + cc;
      const float wx = w1[c*3], wy = w1[c*3+1], wz = w1[c*3+2];
      const float sc = g1[c] * rsqrtf(v1[c] + EPSV);
      float val = px*wx + py*wy + pz*wz + b1[c];
      val = (val - m1[c])*sc + bt1[c];
      hv[cc] = f2b(fmaxf(val, 0.f));
    }
    *(u16x8*)&A1s[g*4096 + swzA1(p, c0)]     = *(u16x8*)&hv[0];
    *(u16x8*)&A1s[g*4096 + swzA1(p, c0 + 8)] = *(u16x8*)&hv[8];
  }
  __syncthreads();

  // ---- L2 (128->256): per wave 32 cols x 3 groups; kt-outer
  {
    const int col0 = w*32;
    f32x4 acc[2][NG3][2];  // [nt][g][m]
    #pragma unroll
    for (int nt = 0; nt < 2; nt++)
      #pragma unroll
      for (int g = 0; g < NG3; g++)
        #pragma unroll
        for (int m = 0; m < 2; m++){ f32x4 z = {0.f,0.f,0.f,0.f}; acc[nt][g][m] = z; }
    #pragma unroll
    for (int kt = 0; kt < 4; kt++){
      bf16x8 bA[NG3][2];
      #pragma unroll
      for (int g = 0; g < NG3; g++)
        #pragma unroll
        for (int m = 0; m < 2; m++)
          bA[g][m] = *(const bf16x8*)&A1s[g*4096 + swzA1(m*16 + lr, kt*32 + lg*8)];
      bf16x8 bB[2];
      #pragma unroll
      for (int nt = 0; nt < 2; nt++)
        bB[nt] = *(const bf16x8*)(w2b + (size_t)(col0 + nt*16 + lr)*128 + kt*32 + lg*8);
      #pragma unroll
      for (int nt = 0; nt < 2; nt++)
        #pragma unroll
        for (int g = 0; g < NG3; g++)
          #pragma unroll
          for (int m = 0; m < 2; m++)
            acc[nt][g][m] = __builtin_amdgcn_mfma_f32_16x16x32_bf16(bA[g][m], bB[nt], acc[nt][g][m], 0,0,0);
    }
    #pragma unroll
    for (int nt = 0; nt < 2; nt++){
      const int col = col0 + nt*16 + lr;
      const float bc = b2[col];
      #pragma unroll
      for (int g = 0; g < NG3; g++)
        #pragma unroll
        for (int m = 0; m < 2; m++)
          #pragma unroll
          for (int r = 0; r < 4; r++)
            Flp[g*8192 + swzF(m*16 + lg*4 + r, col)] = f2b(acc[nt][g][m][r] + bc);
    }
  }
  __syncthreads();

  // ---- fg = max_k f
  for (int it = t; it < NG3*256; it += 512){
    const int g = it >> 8, col = it & 255;
    float mx = -__builtin_inff();
    #pragma unroll 4
    for (int row = 0; row < 32; row++) mx = fmaxf(mx, b2f(Flp[g*8192 + swzF(row, col)]));
    fgb[g*256 + col] = f2b(mx);
  }
  __syncthreads();

  // ---- L3 (512->512): h = [fg bcast | f]; B-frags double-buffered (prefetch kt+1)
  {
    const int col0 = w*64;
    f32x4 acc[4][NG3][2];
    #pragma unroll
    for (int nt = 0; nt < 4; nt++)
      #pragma unroll
      for (int g = 0; g < NG3; g++)
        #pragma unroll
        for (int m = 0; m < 2; m++){ f32x4 z = {0.f,0.f,0.f,0.f}; acc[nt][g][m] = z; }
    bf16x8 bB0[4], bB1[4];
    #pragma unroll
    for (int nt = 0; nt < 4; nt++)
      bB0[nt] = *(const bf16x8*)(w3b + (size_t)(col0 + nt*16 + lr)*512 + lg*8);

#define L3_BODY(KT, BBC) { \
    bf16x8 bA[NG3][2]; \
    if ((KT) < 8){ \
      _Pragma("unroll") \
      for (int g = 0; g < NG3; g++){ \
        const bf16x8 af = *(const bf16x8*)&fgb[g*256 + (KT)*32 + lg*8]; \
        bA[g][0] = af; bA[g][1] = af; \
      } \
    } else { \
      _Pragma("unroll") \
      for (int g = 0; g < NG3; g++) \
        _Pragma("unroll") \
        for (int m = 0; m < 2; m++) \
          bA[g][m] = *(const bf16x8*)&Flp[g*8192 + swzF(m*16 + lr, ((KT)-8)*32 + lg*8)]; \
    } \
    _Pragma("unroll") \
    for (int nt = 0; nt < 4; nt++) \
      _Pragma("unroll") \
      for (int g = 0; g < NG3; g++) \
        _Pragma("unroll") \
        for (int m = 0; m < 2; m++) \
          acc[nt][g][m] = __builtin_amdgcn_mfma_f32_16x16x32_bf16(bA[g][m], (BBC)[nt], acc[nt][g][m], 0,0,0); }

    #pragma unroll
    for (int kp = 0; kp < 8; kp++){
      {
        const int kt = 2*kp;
        #pragma unroll
        for (int nt = 0; nt < 4; nt++)
          bB1[nt] = *(const bf16x8*)(w3b + (size_t)(col0 + nt*16 + lr)*512 + (kt+1)*32 + lg*8);
        L3_BODY(kt, bB0)
      }
      {
        const int kt = 2*kp + 1;
        if (kt < 15){
          #pragma unroll
          for (int nt = 0; nt < 4; nt++)
            bB0[nt] = *(const bf16x8*)(w3b + (size_t)(col0 + nt*16 + lr)*512 + (kt+1)*32 + lg*8);
        }
        L3_BODY(kt, bB1)
      }
    }
#undef L3_BODY
    #pragma unroll
    for (int nt = 0; nt < 4; nt++){
      const int col = col0 + nt*16 + lr;
      const float bc = b3[col];
      const float sc = g3[col]*rsqrtf(v3[col] + EPSV);
      const float mm = m3[col], bb = bt3[col];
      #pragma unroll
      for (int g = 0; g < NG3; g++)
        #pragma unroll
        for (int m = 0; m < 2; m++)
          #pragma unroll
          for (int r = 0; r < 4; r++){
            float val = acc[nt][g][m][r] + bc;
            val = (val - mm)*sc + bb;
            A3s[g*16384 + swzA(m*16 + lg*4 + r, col)] = f2b(fmaxf(val, 0.f));
          }
    }
  }
  __syncthreads();

  // ---- L4 (512->384) + maxpool + b4 -> tok; B-frags double-buffered
  {
    const int col0 = w*48;
    f32x4 acc[3][NG3][2];
    #pragma unroll
    for (int nt = 0; nt < 3; nt++)
      #pragma unroll
      for (int g = 0; g < NG3; g++)
        #pragma unroll
        for (int m = 0; m < 2; m++){ f32x4 z = {0.f,0.f,0.f,0.f}; acc[nt][g][m] = z; }
    bf16x8 bB0[3], bB1[3];
    #pragma unroll
    for (int nt = 0; nt < 3; nt++)
      bB0[nt] = *(const bf16x8*)(w4b + (size_t)(col0 + nt*16 + lr)*512 + lg*8);

#define L4_BODY(KT, BBC) { \
    bf16x8 bA[NG3][2]; \
    _Pragma("unroll") \
    for (int g = 0; g < NG3; g++) \
      _Pragma("unroll") \
      for (int m = 0; m < 2; m++) \
        bA[g][m] = *(const bf16x8*)&A3s[g*16384 + swzA(m*16 + lr, (KT)*32 + lg*8)]; \
    _Pragma("unroll") \
    for (int nt = 0; nt < 3; nt++) \
      _Pragma("unroll") \
      for (int g = 0; g < NG3; g++) \
        _Pragma("unroll") \
        for (int m = 0; m < 2; m++) \
          acc[nt][g][m] = __builtin_amdgcn_mfma_f32_16x16x32_bf16(bA[g][m], (BBC)[nt], acc[nt][g][m], 0,0,0); }

    #pragma unroll
    for (int kp = 0; kp < 8; kp++){
      {
        const int kt = 2*kp;
        #pragma unroll
        for (int nt = 0; nt < 3; nt++)
          bB1[nt] = *(const bf16x8*)(w4b + (size_t)(col0 + nt*16 + lr)*512 + (kt+1)*32 + lg*8);
        L4_BODY(kt, bB0)
      }
      {
        const int kt = 2*kp + 1;
        if (kt < 15){
          #pragma unroll
          for (int nt = 0; nt < 3; nt++)
            bB0[nt] = *(const bf16x8*)(w4b + (size_t)(col0 + nt*16 + lr)*512 + (kt+1)*32 + lg*8);
        }
        L4_BODY(kt, bB1)
      }
    }
#undef L4_BODY
    #pragma unroll
    for (int nt = 0; nt < 3; nt++){
      const int col = col0 + nt*16 + lr;
      const float bc = b4[col];
      #pragma unroll
      for (int g = 0; g < NG3; g++){
        float mx = fmaxf(
          fmaxf(fmaxf(acc[nt][g][0][0], acc[nt][g][0][1]), fmaxf(acc[nt][g][0][2], acc[nt][g][0][3])),
          fmaxf(fmaxf(acc[nt][g][1][0], acc[nt][g][1][1]), fmaxf(acc[nt][g][1][2], acc[nt][g][1][3])));
        mx = fmaxf(mx, __shfl_xor(mx, 16));
        mx = fmaxf(mx, __shfl_xor(mx, 32));
        if (lg == 0) tokp[g*C_ + col] = mx + bc;
      }
    }
  }
  __syncthreads();

  // ---- out = tok + pos_embed(center)   (write-guarded for the tail block)
  #pragma unroll
  for (int g = 0; g < NG3; g++){
    if (g >= ng) break;
    const int gid = gid0 + g;
    for (int c = t; c < C_; c += 512){
      const int d = c >> 7, r = c & 127, m2 = r >> 1;
      const float e = (float)(2*m2) * (1.f/128.f);
      const float dimt = powf(10000.f, e);
      const float ctrd = centers_ord[(size_t)gid*3 + d];
      const float x2 = __fmul_rn(ctrd, 6.28318530717958647692f);
      const float ang = __fdiv_rn(x2, dimt);
      out[(size_t)gid*C_ + c] = tokp[g*C_ + c] + ((r & 1) ? cosf(ang) : sinf(ang));
    }
  }
}

extern "C" void kernel_launch(void* const* d_in, const int* in_sizes, int n_in,
                              void* d_out, int out_size, void* d_ws, size_t ws_size,
                              hipStream_t stream){
  (void)in_sizes; (void)n_in; (void)out_size; (void)ws_size;
  const float* xyz = (const float*)d_in[0];
  const float* w1  = (const float*)d_in[1];
  const float* b1  = (const float*)d_in[2];
  const float* g1  = (const float*)d_in[3];
  const float* bt1 = (const float*)d_in[4];
  const float* m1  = (const float*)d_in[5];
  const float* v1  = (const float*)d_in[6];
  const float* w2  = (const float*)d_in[7];
  const float* b2  = (const float*)d_in[8];
  const float* w3  = (const float*)d_in[9];
  const float* b3  = (const float*)d_in[10];
  const float* g3  = (const float*)d_in[11];
  const float* bt3 = (const float*)d_in[12];
  const float* m3  = (const float*)d_in[13];
  const float* v3  = (const float*)d_in[14];
  const float* w4  = (const float*)d_in[15];
  const float* b4  = (const float*)d_in[16];

  char* ws = (char*)d_ws;
  float* centers_ord  = (float*)(ws + 24576);               // 24576 B
  float* neigh        = (float*)(ws + 49152);               // 786432 B
  unsigned short* w2b = (unsigned short*)(ws + 835584);     // 65536 B
  unsigned short* w3b = (unsigned short*)(ws + 901120);     // 524288 B
  unsigned short* w4b = (unsigned short*)(ws + 1425408);    // 393216 B -> total 1818624 B

  fps_morton_prep_kernel<<<B_ + 1920, 256, 0, stream>>>(xyz, centers_ord,
      w2, w3, w4, w2b, w3b, w4b);
  knn_kernel<<<dim3(G_, B_), 256, 0, stream>>>(xyz, centers_ord, neigh);
  enc_kernel<<<683, 512, 0, stream>>>(neigh, centers_ord,
      w1, b1, g1, bt1, m1, v1, w2b, b2, w3b, b3, g3, bt3, m3, v3, w4b, b4,
      (float*)d_out);
}